// Round 6
// baseline (223.603 us; speedup 1.0000x reference)
//
#include <hip/hip_runtime.h>
#include <math.h>

// feat_gan loss on MI355X (gfx950) — single-dispatch version.
// Shapes fixed by reference setup_inputs():
//   layer0: B=4, N0=4096, C0=64   (xyz [4,4096,3] f32, feat [4,64,4096] f32)
//   layer1: B=4, N1=1024, C1=128
// radius^2 = 1.0, nsample = 1 (first src point within radius; argmax-first).
//
// One wave (64 lanes) per query. Ballot-scan 64 src points/iter; first set
// bit of __ballot = argmax-first index. Per-chunk hit prob ~99.5% for
// N(0,I3) data, so chunk 0 of BOTH ball queries is issued in one parallel
// load round; the fallback loops are the ~0.5% tail. Masked-out queries
// contribute exactly 0 (reference zeroes both gathered groups).
//
// Finalize fused via last-block-done: per-block partial store (PADDED to a
// private 128B cache line per block — no two XCDs dirty the same line in
// their non-coherent L2s) -> __threadfence() release -> ticket atomicAdd
// (device-scope). The ticket lives in d_ws; the harness poisons ws to 0xAA
// before every timed launch, so the counter starts at 0xAAAAAAAA. To be
// robust if the initial correctness call ever sees zeroed ws instead, the
// winner test accepts EITHER start value (the two old-value ranges are
// disjoint, so exactly one block wins in either regime).

#define RAD2 1.0f

constexpr int B  = 4;
constexpr int N0 = 4096, C0 = 64;
constexpr int N1 = 1024, C1 = 128;
constexpr int W0 = B * N0;            // 16384 queries in layer0
constexpr int W1 = B * N1;            // 4096 in layer1
constexpr int WPB  = 4;               // waves (queries) per 256-thread block
constexpr int NB0  = W0 / WPB;        // 4096 blocks -> layer0
constexpr int NB1  = W1 / WPB;        // 1024 blocks -> layer1
constexpr int NBLK = NB0 + NB1;       // 5120
constexpr int PSTRIDE = 16;           // doubles per partial slot = 128 B line
constexpr unsigned POISON_U32 = 0xAAAAAAAAu;   // ws poison pattern as u32

template<int C, int N, int LOGN>
__device__ __forceinline__ float query_loss_wave(
    const float* __restrict__ att_xyz,   // [B,N,3]
    const float* __restrict__ bat_xyz,   // [B,N,3]
    const float* __restrict__ att_feat,  // [B,C,N]
    const float* __restrict__ bat_feat,  // [B,C,N]
    int gq, int lane)
{
    const int b = gq >> LOGN;
    const int n = gq & (N - 1);
    const float* aq = att_xyz + (size_t)b * N * 3;
    const float* bq = bat_xyz + (size_t)b * N * 3;

    // query point (wave-uniform)
    const float qx = bq[n * 3 + 0];
    const float qy = bq[n * 3 + 1];
    const float qz = bq[n * 3 + 2];

    // chunk 0 of BOTH ball queries, issued in one load round
    const float dax = qx - aq[lane * 3 + 0];
    const float day = qy - aq[lane * 3 + 1];
    const float daz = qz - aq[lane * 3 + 2];
    const float dbx = qx - bq[lane * 3 + 0];
    const float dby = qy - bq[lane * 3 + 1];
    const float dbz = qz - bq[lane * 3 + 2];
    const unsigned long long balA = __ballot(dax * dax + day * day + daz * daz < RAD2);
    const unsigned long long balB = __ballot(dbx * dbx + dby * dby + dbz * dbz < RAD2);

    // --- att ball query: first m with d2 < 1 (this also defines the mask) ---
    int att_idx = -1;
    if (balA) {
        att_idx = (int)__builtin_ctzll(balA);
    } else {
        for (int c0 = 64; c0 < N; c0 += 64) {
            const int m = c0 + lane;
            const float dx = qx - aq[m * 3 + 0];
            const float dy = qy - aq[m * 3 + 1];
            const float dz = qz - aq[m * 3 + 2];
            const unsigned long long bal = __ballot(dx * dx + dy * dy + dz * dz < RAD2);
            if (bal) { att_idx = c0 + (int)__builtin_ctzll(bal); break; }
        }
    }
    if (att_idx < 0) return 0.0f;          // mask=false -> exact zero contribution

    // --- bat (self) ball query: guaranteed hit at m <= n ---
    int bat_idx = n;
    if (balB) {
        bat_idx = (int)__builtin_ctzll(balB);
    } else {                                // balB==0 implies n >= 64
        for (int c0 = 64; c0 < N; c0 += 64) {
            const int m = c0 + lane;
            const float dx = qx - bq[m * 3 + 0];
            const float dy = qy - bq[m * 3 + 1];
            const float dz = qz - bq[m * 3 + 2];
            const unsigned long long bal = __ballot(dx * dx + dy * dy + dz * dz < RAD2);
            if (bal) { bat_idx = c0 + (int)__builtin_ctzll(bal); break; }
        }
    }

    // --- gather + squared diff: lanes 0-2 xyz, lane c feature channel c ---
    float part = 0.0f;
    if (lane < 3) {
        const float d = aq[att_idx * 3 + lane] - bq[bat_idx * 3 + lane];
        part = d * d;
    }
    const float* af = att_feat + (size_t)b * C * N;
    const float* bf = bat_feat + (size_t)b * C * N;
    #pragma unroll
    for (int c = lane; c < C; c += 64) {
        const float d = af[c * N + att_idx] - bf[c * N + bat_idx];
        part += d * d;
    }
    return part;
}

__global__ __launch_bounds__(256) void fg_onepass_kernel(
    const float* __restrict__ att_xyz0, const float* __restrict__ bat_xyz0,
    const float* __restrict__ att_feat0, const float* __restrict__ bat_feat0,
    const float* __restrict__ att_xyz1, const float* __restrict__ bat_xyz1,
    const float* __restrict__ att_feat1, const float* __restrict__ bat_feat1,
    double* __restrict__ partials,       // [NBLK * PSTRIDE] in d_ws (padded)
    unsigned* __restrict__ cnt,          // ticket counter in d_ws
    float* __restrict__ out)
{
    const int lane = threadIdx.x & 63;
    const int wid  = threadIdx.x >> 6;
    const int blk  = blockIdx.x;

    float part;
    if (blk < NB0) {      // block-uniform layer split (NB0*WPB == W0)
        const int gw = blk * WPB + wid;
        part = query_loss_wave<C0, N0, 12>(att_xyz0, bat_xyz0, att_feat0,
                                           bat_feat0, gw, lane);
    } else {
        const int gw = (blk - NB0) * WPB + wid;
        part = query_loss_wave<C1, N1, 10>(att_xyz1, bat_xyz1, att_feat1,
                                           bat_feat1, gw, lane);
    }

    // wave reduce (64 lanes)
    #pragma unroll
    for (int off = 32; off > 0; off >>= 1)
        part += __shfl_down(part, off);

    __shared__ double wpart[WPB];
    __shared__ int is_last;
    if (lane == 0) wpart[wid] = (double)part;
    __syncthreads();
    if (threadIdx.x == 0) {
        // private 128B line per block: no cross-XCD false sharing on writeback
        partials[(size_t)blk * PSTRIDE] = wpart[0] + wpart[1] + wpart[2] + wpart[3];
        __threadfence();   // release: agent-scope writeback before the ticket
        const unsigned old = atomicAdd(cnt, 1u);
        // winner under poison-start (normal) OR zero-start (defensive);
        // the two old-value ranges are disjoint, so exactly one block wins
        is_last = (old == POISON_U32 + (unsigned)NBLK - 1u) ||
                  (old == (unsigned)NBLK - 1u);
    }
    __syncthreads();
    if (!is_last) return;                 // block-uniform; winner keeps 256 threads

    // ---- last block: final reduction + loss ----
    __threadfence();                      // acquire: order after all releases
    const int t = threadIdx.x;
    double s0 = 0.0, s1 = 0.0;
    for (int i = t; i < NB0; i += 256)
        s0 += partials[(size_t)i * PSTRIDE];
    for (int i = NB0 + t; i < NBLK; i += 256)
        s1 += partials[(size_t)i * PSTRIDE];

    #pragma unroll
    for (int off = 32; off > 0; off >>= 1) {
        s0 += __shfl_down(s0, off);
        s1 += __shfl_down(s1, off);
    }
    __shared__ double sh0[WPB], sh1[WPB];
    if (lane == 0) { sh0[wid] = s0; sh1[wid] = s1; }
    __syncthreads();
    if (t == 0) {
        const double a0 = sh0[0] + sh0[1] + sh0[2] + sh0[3];
        const double a1 = sh1[0] + sh1[1] + sh1[2] + sh1[3];
        const double l0 = a0 * (1.0 / 1097728.0);   // 1/(4*4096*67)
        const double l1 = a1 * (1.0 / 536576.0);    // 1/(4*1024*131)
        double loss = 0.5 * (l0 + l1);
        if (isnan(loss)) loss = l1;   // reference: where(isnan, losses[-1], loss)
        out[0] = (float)loss;
    }
}

extern "C" void kernel_launch(void* const* d_in, const int* in_sizes, int n_in,
                              void* d_out, int out_size, void* d_ws, size_t ws_size,
                              hipStream_t stream) {
    // setup_inputs order:
    // 0 att_xyz0  1 att_xyz1  2 bat_xyz0  3 bat_xyz1
    // 4 att_feat0 5 att_feat1 6 bat_feat0 7 bat_feat1
    const float* att_xyz0  = (const float*)d_in[0];
    const float* att_xyz1  = (const float*)d_in[1];
    const float* bat_xyz0  = (const float*)d_in[2];
    const float* bat_xyz1  = (const float*)d_in[3];
    const float* att_feat0 = (const float*)d_in[4];
    const float* att_feat1 = (const float*)d_in[5];
    const float* bat_feat0 = (const float*)d_in[6];
    const float* bat_feat1 = (const float*)d_in[7];
    float* out = (float*)d_out;

    double*   partials = (double*)d_ws;   // NBLK*16 doubles = 640 KiB, padded
    unsigned* cnt = (unsigned*)((char*)d_ws + (size_t)NBLK * PSTRIDE * sizeof(double));

    fg_onepass_kernel<<<NBLK, 256, 0, stream>>>(
        att_xyz0, bat_xyz0, att_feat0, bat_feat0,
        att_xyz1, bat_xyz1, att_feat1, bat_feat1,
        partials, cnt, out);
}

// Round 9
// 113.710 us; speedup vs baseline: 1.9664x; 1.9664x over previous
//
#include <hip/hip_runtime.h>
#include <math.h>

// feat_gan loss on MI355X (gfx950) — two-dispatch, 4-queries-per-wave.
//
// Measured history: two-dispatch 1-query/wave = 110.25 µs total (round 3,
// absmax 0.0); single-dispatch threadfence variant = 223.6 µs (round 6 —
// __threadfence agent-release is a full XCD-L2 writeback on gfx950, 5120 of
// them serialized the kernel; never fuse via last-block-done here).
//
// Shapes fixed by reference setup_inputs():
//   layer0: B=4, N0=4096, C0=64   (xyz [4,4096,3] f32, feat [4,64,4096] f32)
//   layer1: B=4, N1=1024, C1=128
// radius^2 = 1.0, nsample = 1 (first src point within radius; argmax-first).
//
// One wave handles 4 CONSECUTIVE queries of one batch:
//  - chunk-0 ballot source points (aq[lane], bq[lane]) loaded ONCE, reused
//    by all 4 queries (they share the batch) -> 4x fewer ballot-phase loads;
//  - 4 independent query chains give 4x memory-level parallelism in the
//    ballot and gather phases (this kernel is latency-bound, not BW-bound);
//  - per-chunk hit prob ~99.5% per query, so the fallback scan is a ~2%/wave
//    tail; mask=false has prob ~e^-341 on this data but is handled exactly
//    (branchless clamped-index + 0/1 weight, matching the reference's zeroed
//    groups).
// Blocks never straddle a batch or layer: 16 queries/block divides 4096 and
// 1024. Each wave writes one double partial; kernel 2 reduces 5120 partials.

#define RAD2 1.0f

constexpr int B  = 4;
constexpr int N0 = 4096, C0 = 64;
constexpr int N1 = 1024, C1 = 128;
constexpr int W0 = B * N0;            // 16384 queries in layer0
constexpr int W1 = B * N1;            // 4096 in layer1
constexpr int QPW = 4;                // queries per wave
constexpr int WPB = 4;                // waves per 256-thread block
constexpr int NWV0 = W0 / QPW;        // 4096 layer0 waves
constexpr int NWV1 = W1 / QPW;        // 1024 layer1 waves
constexpr int NWVT = NWV0 + NWV1;     // 5120 partials
constexpr int NBLK = NWVT / WPB;      // 1280 blocks

template<int C, int N, int LOGN>
__device__ __forceinline__ float quad_loss_wave(
    const float* __restrict__ att_xyz,   // [B,N,3]
    const float* __restrict__ bat_xyz,   // [B,N,3]
    const float* __restrict__ att_feat,  // [B,C,N]
    const float* __restrict__ bat_feat,  // [B,C,N]
    int gq0, int lane)                   // gq0 = first of 4 consecutive queries
{
    const int b  = gq0 >> LOGN;
    const int n0 = gq0 & (N - 1);        // n0..n0+3 all in batch b
    const float* aq = att_xyz + (size_t)b * N * 3;
    const float* bq = bat_xyz + (size_t)b * N * 3;

    // chunk-0 source points: loaded once, shared by all 4 queries
    const float ax = aq[lane * 3 + 0];
    const float ay = aq[lane * 3 + 1];
    const float az = aq[lane * 3 + 2];
    const float bx = bq[lane * 3 + 0];
    const float by = bq[lane * 3 + 1];
    const float bz = bq[lane * 3 + 2];

    // 4 query points (independent wave-uniform loads, issued together)
    float qx[QPW], qy[QPW], qz[QPW];
    #pragma unroll
    for (int q = 0; q < QPW; ++q) {
        qx[q] = bq[(n0 + q) * 3 + 0];
        qy[q] = bq[(n0 + q) * 3 + 1];
        qz[q] = bq[(n0 + q) * 3 + 2];
    }

    int att_idx[QPW], bat_idx[QPW];
    #pragma unroll
    for (int q = 0; q < QPW; ++q) {
        const float dax = qx[q] - ax, day = qy[q] - ay, daz = qz[q] - az;
        const float dbx = qx[q] - bx, dby = qy[q] - by, dbz = qz[q] - bz;
        const unsigned long long balA =
            __ballot(dax * dax + day * day + daz * daz < RAD2);
        const unsigned long long balB =
            __ballot(dbx * dbx + dby * dby + dbz * dbz < RAD2);
        att_idx[q] = balA ? (int)__builtin_ctzll(balA) : -1;
        bat_idx[q] = balB ? (int)__builtin_ctzll(balB) : (n0 + q); // self fallback

        // rare tail (~0.5%/query): scan remaining chunks for whichever missed
        if (!balA || !balB) {
            bool needA = !balA, needB = !balB;
            for (int c0 = 64; c0 < N && (needA || needB); c0 += 64) {
                const int m = c0 + lane;
                if (needA) {
                    const float dx = qx[q] - aq[m * 3 + 0];
                    const float dy = qy[q] - aq[m * 3 + 1];
                    const float dz = qz[q] - aq[m * 3 + 2];
                    const unsigned long long bal =
                        __ballot(dx * dx + dy * dy + dz * dz < RAD2);
                    if (bal) { att_idx[q] = c0 + (int)__builtin_ctzll(bal); needA = false; }
                }
                if (needB) {
                    const float dx = qx[q] - bq[m * 3 + 0];
                    const float dy = qy[q] - bq[m * 3 + 1];
                    const float dz = qz[q] - bq[m * 3 + 2];
                    const unsigned long long bal =
                        __ballot(dx * dx + dy * dy + dz * dz < RAD2);
                    if (bal) { bat_idx[q] = c0 + (int)__builtin_ctzll(bal); needB = false; }
                    // guaranteed to fire by the chunk containing n0+q (self d2=0)
                }
            }
        }
    }

    // branchless gather: clamped index + 0/1 weight (mask=false -> weight 0,
    // matching the reference's zeroed groups exactly: 0*anything = 0, and
    // gathered values are finite so no NaN leakage)
    const float* af = att_feat + (size_t)b * C * N;
    const float* bf = bat_feat + (size_t)b * C * N;
    float part = 0.0f;
    #pragma unroll
    for (int q = 0; q < QPW; ++q) {
        const float w  = (att_idx[q] < 0) ? 0.0f : 1.0f;
        const int   ia = (att_idx[q] < 0) ? 0    : att_idx[q];
        const int   ib = bat_idx[q];
        float pq = 0.0f;
        if (lane < 3) {
            const float d = aq[ia * 3 + lane] - bq[ib * 3 + lane];
            pq = d * d;
        }
        #pragma unroll
        for (int c = lane; c < C; c += 64) {
            const float d = af[c * N + ia] - bf[c * N + ib];
            pq += d * d;
        }
        part += w * pq;
    }
    return part;
}

__global__ __launch_bounds__(256) void fg_fused_kernel(
    const float* __restrict__ att_xyz0, const float* __restrict__ bat_xyz0,
    const float* __restrict__ att_feat0, const float* __restrict__ bat_feat0,
    const float* __restrict__ att_xyz1, const float* __restrict__ bat_xyz1,
    const float* __restrict__ att_feat1, const float* __restrict__ bat_feat1,
    double* __restrict__ partials)       // [NWVT], one double per wave
{
    const int lane = threadIdx.x & 63;
    const int gwv  = blockIdx.x * WPB + (threadIdx.x >> 6);  // global wave id

    float part;
    if (gwv < NWV0)   // block-uniform (NWV0 % WPB == 0)
        part = quad_loss_wave<C0, N0, 12>(att_xyz0, bat_xyz0, att_feat0,
                                          bat_feat0, gwv * QPW, lane);
    else
        part = quad_loss_wave<C1, N1, 10>(att_xyz1, bat_xyz1, att_feat1,
                                          bat_feat1, (gwv - NWV0) * QPW, lane);

    // wave reduce (64 lanes), then one store per wave — no LDS, no barrier
    #pragma unroll
    for (int off = 32; off > 0; off >>= 1)
        part += __shfl_down(part, off);
    if (lane == 0) partials[gwv] = (double)part;
}

__global__ __launch_bounds__(1024) void fg_finalize_kernel(
    const double* __restrict__ partials,
    float* __restrict__ out)
{
    const int t = threadIdx.x;
    double s0 = 0.0, s1 = 0.0;
    #pragma unroll 4
    for (int i = t; i < NWV0; i += 1024) s0 += partials[i];
    for (int i = NWV0 + t; i < NWVT; i += 1024) s1 += partials[i];

    #pragma unroll
    for (int off = 32; off > 0; off >>= 1) {
        s0 += __shfl_down(s0, off);
        s1 += __shfl_down(s1, off);
    }

    __shared__ double sh0[16], sh1[16];
    const int lane = t & 63, w = t >> 6;
    if (lane == 0) { sh0[w] = s0; sh1[w] = s1; }
    __syncthreads();
    if (t == 0) {
        double a0 = 0.0, a1 = 0.0;
        #pragma unroll
        for (int i = 0; i < 16; ++i) { a0 += sh0[i]; a1 += sh1[i]; }
        const double l0 = a0 * (1.0 / 1097728.0);   // 1/(4*4096*67)
        const double l1 = a1 * (1.0 / 536576.0);    // 1/(4*1024*131)
        double loss = 0.5 * (l0 + l1);
        if (isnan(loss)) loss = l1;   // reference: where(isnan, losses[-1], loss)
        out[0] = (float)loss;
    }
}

extern "C" void kernel_launch(void* const* d_in, const int* in_sizes, int n_in,
                              void* d_out, int out_size, void* d_ws, size_t ws_size,
                              hipStream_t stream) {
    // setup_inputs order:
    // 0 att_xyz0  1 att_xyz1  2 bat_xyz0  3 bat_xyz1
    // 4 att_feat0 5 att_feat1 6 bat_feat0 7 bat_feat1
    const float* att_xyz0  = (const float*)d_in[0];
    const float* att_xyz1  = (const float*)d_in[1];
    const float* bat_xyz0  = (const float*)d_in[2];
    const float* bat_xyz1  = (const float*)d_in[3];
    const float* att_feat0 = (const float*)d_in[4];
    const float* att_feat1 = (const float*)d_in[5];
    const float* bat_feat0 = (const float*)d_in[6];
    const float* bat_feat1 = (const float*)d_in[7];
    float* out = (float*)d_out;

    double* partials = (double*)d_ws;   // NWVT doubles = 40 KiB scratch

    fg_fused_kernel<<<NBLK, 256, 0, stream>>>(
        att_xyz0, bat_xyz0, att_feat0, bat_feat0,
        att_xyz1, bat_xyz1, att_feat1, bat_feat1, partials);

    fg_finalize_kernel<<<1, 1024, 0, stream>>>(partials, out);
}